// Round 2
// baseline (3148.168 us; speedup 1.0000x reference)
//
#include <hip/hip_runtime.h>
#include <cstdint>
#include <cstddef>

// Problem dims
#define NF 64
#define NH 256
#define NW 256
#define NC 64
#define KHH 3
#define KWW 3
#define HOUT 254
#define WOUT 254
#define JT 4                       // output rows per thread
#define JCH 64                     // ceil(254/4)
#define NBLK (NF * JCH)            // 4096 blocks

// Input encoding flag lives in d_ws[0]: 0 = int8 packed, 1 = int32, 2 = float32
__global__ void detect_kernel(const unsigned int* __restrict__ x,
                              int* __restrict__ flagp) {
    if (threadIdx.x != 0 || blockIdx.x != 0) return;
    int c32 = 0, cf = 0;
    for (int i = 0; i < 64; ++i) {
        unsigned int v = x[i];
        unsigned int hi = v >> 8;
        if (hi == 0u || hi == 0x00FFFFFFu) c32++;   // int32 in [-128,127]
        float f = __uint_as_float(v);
        if (f == truncf(f) && f >= -129.0f && f <= 128.0f &&
            (v == 0u || fabsf(f) >= 1.0f)) cf++;    // small integral float
    }
    flagp[0] = (c32 == 64) ? 1 : ((cf == 64) ? 2 : 0);
}

__device__ __forceinline__ int dot4(int a, int b, int c) {
#if __has_builtin(__builtin_amdgcn_sdot4)
    return __builtin_amdgcn_sdot4(a, b, c, false);
#else
    #pragma unroll
    for (int i = 0; i < 4; ++i) {
        int ai = (int)(signed char)(a >> (8 * i));
        int bi = (int)(signed char)(b >> (8 * i));
        c += ai * bi;
    }
    return c;
#endif
}

__device__ __forceinline__ int comp4(const int4 v, int c) {
    return c == 0 ? v.x : (c == 1 ? v.y : (c == 2 ? v.z : v.w));
}

// Faithful TFLite-style requant: ((acc*rmant + rnd) >> tsh) + zp, clip int8.
__device__ __forceinline__ int requant(int acc, int rmant, int tsh,
                                       long long rnd, int zp) {
    long long a = (long long)acc * (long long)rmant + rnd;
    long long r = a >> tsh;   // arithmetic shift, matches int64 right_shift
    r += zp;
    if (r < -128) r = -128;
    if (r > 127) r = 127;
    return (int)r;
}

// ---------------- Path A: x/w stored as raw int8 bytes ----------------
__global__ __launch_bounds__(256) void conv_i8(
    const signed char* __restrict__ x, const int* __restrict__ w,
    const int* __restrict__ bias, const int* __restrict__ qmp,
    const int* __restrict__ exp_p, const int* __restrict__ zpp,
    int* __restrict__ out, const int* __restrict__ flagp) {
    if (flagp[0] != 0) return;
    __shared__ int ws[144];  // 3*3*64 int8 = 576 B = 144 dwords
    int bid = blockIdx.x;
    int vid = ((bid & 7) << 9) | (bid >> 3);  // XCD swizzle
    int f = vid >> 6;
    int jc = vid & 63;
    int tid = threadIdx.x;
    if (tid < 144) ws[tid] = w[f * 144 + tid];
    __syncthreads();
    int k = tid;
    if (k >= WOUT) return;
    int j0 = jc * JT;
    int acc[JT] = {0, 0, 0, 0};
    const int4* xbase = (const int4*)(x + (((size_t)f * NH + j0) * NW + k) * NC);
    const int4* ws4 = (const int4*)ws;
    #pragma unroll
    for (int r = 0; r < JT + KHH - 1; ++r) {  // x row j0 + r
        int j = j0 + r;
        if (j < NH) {
            int4 xv[12];  // cols k..k+2, 64 ch each = 192 B
            #pragma unroll
            for (int t = 0; t < 12; ++t)
                xv[t] = xbase[(size_t)r * (NW * NC / 16) + t];
            #pragma unroll
            for (int m = 0; m < KHH; ++m) {
                const int jo = r - m;
                if (jo >= 0 && jo < JT) {
                    #pragma unroll
                    for (int n = 0; n < KWW; ++n) {
                        #pragma unroll
                        for (int q = 0; q < 4; ++q) {
                            int4 wv = ws4[(m * 3 + n) * 4 + q];
                            #pragma unroll
                            for (int b = 0; b < 4; ++b)
                                acc[jo] = dot4(comp4(xv[n * 4 + q], b),
                                               comp4(wv, b), acc[jo]);
                        }
                    }
                }
            }
        }
    }
    int qm = qmp[0], ex = exp_p[0], zp = zpp[0];
    int rmant = (qm < 2147418112) ? ((qm + 32768) >> 16) : 32767;
    int tsh = 15 - ex;
    long long rnd = 1LL << (tsh - 1);
    int bv = bias[f];
    #pragma unroll
    for (int jo = 0; jo < JT; ++jo) {
        int j = j0 + jo;
        if (j < HOUT)
            out[((size_t)f * HOUT + j) * WOUT + k] =
                requant(acc[jo] + bv, rmant, tsh, rnd, zp);
    }
}

// -------- Path B/C: x/w promoted to int32 (T=int) or float32 (T=float) -----
template <typename T>
__global__ __launch_bounds__(256) void conv_gen(
    const T* __restrict__ x, const T* __restrict__ w,
    const int* __restrict__ bias, const int* __restrict__ qmp,
    const int* __restrict__ exp_p, const int* __restrict__ zpp,
    int* __restrict__ out, const int* __restrict__ flagp, int myflag) {
    if (flagp[0] != myflag) return;
    __shared__ int ws[576];
    int bid = blockIdx.x;
    int vid = ((bid & 7) << 9) | (bid >> 3);
    int f = vid >> 6;
    int jc = vid & 63;
    int tid = threadIdx.x;
    for (int i = tid; i < 576; i += 256)
        ws[i] = (int)w[(size_t)f * 576 + i];
    __syncthreads();
    int k = tid;
    if (k >= WOUT) return;
    int j0 = jc * JT;
    int acc[JT] = {0, 0, 0, 0};
    #pragma unroll
    for (int r = 0; r < JT + KHH - 1; ++r) {
        int j = j0 + r;
        if (j < NH) {
            const T* xr = x + (((size_t)f * NH + j) * NW + k) * NC;
            #pragma unroll
            for (int n = 0; n < KWW; ++n) {
                #pragma unroll
                for (int c0 = 0; c0 < NC; c0 += 16) {
                    int xt[16];
                    #pragma unroll
                    for (int c = 0; c < 16; ++c)
                        xt[c] = (int)xr[n * NC + c0 + c];
                    #pragma unroll
                    for (int m = 0; m < KHH; ++m) {
                        const int jo = r - m;
                        if (jo >= 0 && jo < JT) {
                            #pragma unroll
                            for (int c = 0; c < 16; ++c)
                                acc[jo] += xt[c] * ws[(m * 3 + n) * 64 + c0 + c];
                        }
                    }
                }
            }
        }
    }
    int qm = qmp[0], ex = exp_p[0], zp = zpp[0];
    int rmant = (qm < 2147418112) ? ((qm + 32768) >> 16) : 32767;
    int tsh = 15 - ex;
    long long rnd = 1LL << (tsh - 1);
    int bv = bias[f];
    #pragma unroll
    for (int jo = 0; jo < JT; ++jo) {
        int j = j0 + jo;
        if (j < HOUT)
            out[((size_t)f * HOUT + j) * WOUT + k] =
                requant(acc[jo] + bv, rmant, tsh, rnd, zp);
    }
}

extern "C" void kernel_launch(void* const* d_in, const int* in_sizes, int n_in,
                              void* d_out, int out_size, void* d_ws,
                              size_t ws_size, hipStream_t stream) {
    (void)in_sizes; (void)n_in; (void)ws_size; (void)out_size;
    const void* x = d_in[0];
    const void* w = d_in[1];
    const int* bias = (const int*)d_in[2];
    const int* qm = (const int*)d_in[3];
    const int* ex = (const int*)d_in[4];
    const int* zp = (const int*)d_in[5];
    int* out = (int*)d_out;
    int* flagp = (int*)d_ws;

    detect_kernel<<<1, 64, 0, stream>>>((const unsigned int*)x, flagp);
    conv_i8<<<NBLK, 256, 0, stream>>>((const signed char*)x, (const int*)w,
                                      bias, qm, ex, zp, out, flagp);
    conv_gen<int><<<NBLK, 256, 0, stream>>>((const int*)x, (const int*)w,
                                            bias, qm, ex, zp, out, flagp, 1);
    conv_gen<float><<<NBLK, 256, 0, stream>>>((const float*)x, (const float*)w,
                                              bias, qm, ex, zp, out, flagp, 2);
}

// Round 3
// 1358.508 us; speedup vs baseline: 2.3174x; 2.3174x over previous
//
#include <hip/hip_runtime.h>
#include <cstdint>
#include <cstddef>

// Problem dims
#define NF 64
#define NH 256
#define NW 256
#define NC 64
#define HOUT 254
#define WOUT 254
#define JR 32                 // output rows per block strip
#define NCHUNK 8              // ceil(254/32)
#define NBLK (NF * NCHUNK)    // 512 blocks

// ---------------- input-encoding detection (d_ws[0]) ----------------
// 1 = int32 values, 2 = float32 values (int8 raw ruled out in round 2)
__global__ void detect_kernel(const unsigned int* __restrict__ x,
                              int* __restrict__ flagp) {
    if (threadIdx.x != 0 || blockIdx.x != 0) return;
    int c32 = 0, cf = 0;
    for (int i = 0; i < 64; ++i) {
        unsigned int v = x[i];
        unsigned int hi = v >> 8;
        if (hi == 0u || hi == 0x00FFFFFFu) c32++;   // int32 in [-128,127]
        float f = __uint_as_float(v);
        if (f == truncf(f) && f >= -129.0f && f <= 128.0f &&
            (v == 0u || fabsf(f) >= 1.0f)) cf++;    // small integral float
    }
    flagp[0] = (c32 == 64) ? 1 : ((cf == 64) ? 2 : 0);
}

__device__ __forceinline__ int dot4(int a, int b, int c) {
#if __has_builtin(__builtin_amdgcn_sdot4)
    return __builtin_amdgcn_sdot4(a, b, c, false);
#else
    #pragma unroll
    for (int i = 0; i < 4; ++i)
        c += (int)(signed char)(a >> (8 * i)) * (int)(signed char)(b >> (8 * i));
    return c;
#endif
}

// pack 4 consecutive values (known to be in [-128,127]) into one int8x4 dword
__device__ __forceinline__ int pack4(const int* p) {
    int4 v = *(const int4*)p;
    return (v.x & 255) | ((v.y & 255) << 8) | ((v.z & 255) << 16) | (v.w << 24);
}
__device__ __forceinline__ int pack4(const float* p) {
    float4 v = *(const float4*)p;
    int a = (int)v.x, b = (int)v.y, c = (int)v.z, d = (int)v.w;
    return (a & 255) | ((b & 255) << 8) | ((c & 255) << 16) | (d << 24);
}

// LDS x-row buffer layout: [q4 (4)][col (256)][q_lo (4 dwords)] = 4096 dwords.
// Compute reads ds_read_b128 at int4 index q4*256 + col: dense, 16B-aligned.
template <typename T>
__device__ __forceinline__ void conv_body(
    const T* __restrict__ x, const T* __restrict__ w,
    const int* __restrict__ bias, const int* __restrict__ qmp,
    const int* __restrict__ exp_p, const int* __restrict__ zpp,
    int* __restrict__ out) {
    __shared__ int xlds[4 * 4096];   // 4 rotating row buffers, 64 KB
    __shared__ int wlds[144];        // packed weights for this f

    const int tid = threadIdx.x;
    const int bid = blockIdx.x;
    const int f = bid >> 3;
    const int j0 = (bid & 7) * JR;
    const int nout = min(JR, HOUT - j0);

    if (tid < 144) wlds[tid] = pack4(w + (size_t)f * 576 + tid * 4);
    __syncthreads();

    // weights -> registers (144 VGPRs; LDS caps us at 2 waves/SIMD so this
    // is free — __launch_bounds__(256,2) on the wrappers)
    int4 W[9][4];
    #pragma unroll
    for (int t = 0; t < 9; ++t)
        #pragma unroll
        for (int q4 = 0; q4 < 4; ++q4)
            W[t][q4] = *(const int4*)&wlds[t * 16 + q4 * 4];

    const int qm = qmp[0], ex = exp_p[0], zp = zpp[0];
    const int rmant = (qm < 2147418112) ? ((qm + 32768) >> 16) : 32767;
    const int tsh = 15 - ex;
    const long long rnd = 1LL << (tsh - 1);
    const int bv = bias[f];
    const int k = tid;

    for (int r = 0; r < nout + 2; ++r) {
        // ---- stage x row (f, j0+r) into buffer r&3, coalesced ----
        {
            const T* xr = x + (size_t)(f * NH + (j0 + r)) * (NW * NC);
            int* dst = xlds + (r & 3) * 4096;
            #pragma unroll
            for (int i = 0; i < 16; ++i) {
                int g = i * 256 + tid;          // int8x4 group index in row
                int packed = pack4(xr + (size_t)g * 4);
                int col = g >> 4, q = g & 15;
                dst[(q >> 2) * 1024 + col * 4 + (q & 3)] = packed;
            }
        }
        __syncthreads();
        // ---- compute output row j0+r-2 from buffers (r-2..r)&3 ----
        if (r >= 2 && k < WOUT) {
            const int jo = j0 + r - 2;
            int a0 = 0, a1 = 0, a2 = 0, a3 = 0;
            #pragma unroll
            for (int m = 0; m < 3; ++m) {
                const int4* bm = (const int4*)(xlds + ((r - 2 + m) & 3) * 4096);
                #pragma unroll
                for (int n = 0; n < 3; ++n) {
                    #pragma unroll
                    for (int q4 = 0; q4 < 4; ++q4) {
                        int4 xv = bm[q4 * 256 + k + n];
                        int4 wv = W[m * 3 + n][q4];
                        a0 = dot4(xv.x, wv.x, a0);
                        a1 = dot4(xv.y, wv.y, a1);
                        a2 = dot4(xv.z, wv.z, a2);
                        a3 = dot4(xv.w, wv.w, a3);
                    }
                }
            }
            long long a = (long long)(a0 + a1 + a2 + a3 + bv) * rmant + rnd;
            long long res = (a >> tsh) + zp;
            res = res < -128 ? -128 : (res > 127 ? 127 : res);
            out[((size_t)f * HOUT + jo) * WOUT + k] = (int)res;
        }
    }
}

__global__ __launch_bounds__(256, 2) void conv_i32(
    const int* __restrict__ x, const int* __restrict__ w,
    const int* __restrict__ bias, const int* __restrict__ qmp,
    const int* __restrict__ exp_p, const int* __restrict__ zpp,
    int* __restrict__ out, const int* __restrict__ flagp) {
    if (flagp[0] != 1) return;
    conv_body<int>(x, w, bias, qmp, exp_p, zpp, out);
}

__global__ __launch_bounds__(256, 2) void conv_f32(
    const float* __restrict__ x, const float* __restrict__ w,
    const int* __restrict__ bias, const int* __restrict__ qmp,
    const int* __restrict__ exp_p, const int* __restrict__ zpp,
    int* __restrict__ out, const int* __restrict__ flagp) {
    if (flagp[0] != 2) return;
    conv_body<float>(x, w, bias, qmp, exp_p, zpp, out);
}

extern "C" void kernel_launch(void* const* d_in, const int* in_sizes, int n_in,
                              void* d_out, int out_size, void* d_ws,
                              size_t ws_size, hipStream_t stream) {
    (void)in_sizes; (void)n_in; (void)ws_size; (void)out_size;
    const void* x = d_in[0];
    const void* w = d_in[1];
    const int* bias = (const int*)d_in[2];
    const int* qm = (const int*)d_in[3];
    const int* ex = (const int*)d_in[4];
    const int* zp = (const int*)d_in[5];
    int* out = (int*)d_out;
    int* flagp = (int*)d_ws;

    detect_kernel<<<1, 64, 0, stream>>>((const unsigned int*)x, flagp);
    conv_i32<<<NBLK, 256, 0, stream>>>((const int*)x, (const int*)w,
                                       bias, qm, ex, zp, out, flagp);
    conv_f32<<<NBLK, 256, 0, stream>>>((const float*)x, (const float*)w,
                                       bias, qm, ex, zp, out, flagp);
}